// Round 1
// baseline (993.431 us; speedup 1.0000x reference)
//
#include <hip/hip_runtime.h>
#include <hip/hip_bf16.h>
#include <math.h>

#define T_SEQ 2048
#define HID   4096
#define NH    32
#define NKV   8
#define HD    128
#define QKVD  6144
#define KOFF  4096
#define VOFF  5120

typedef unsigned short u16;
typedef unsigned int   u32;
typedef __attribute__((ext_vector_type(4))) float f32x4;
typedef __attribute__((ext_vector_type(8))) short s16x8;
typedef __attribute__((ext_vector_type(4))) unsigned short u16x4;

__device__ inline u16 f2bf(float f) {
  u32 u = __float_as_uint(f);
  u32 r = u + 0x7FFFu + ((u >> 16) & 1u);
  return (u16)(r >> 16);
}
__device__ inline float bf2f(u16 h) { return __uint_as_float(((u32)h) << 16); }

__device__ inline void gl_lds16(const void* g, void* l) {
  __builtin_amdgcn_global_load_lds((const __attribute__((address_space(1))) void*)g,
                                   (__attribute__((address_space(3))) void*)l, 16, 0, 0);
}

// ---------------- cast fp32 -> bf16 (vectorized) ----------------
__global__ void cast_f32_bf16(const float* __restrict__ in, u16* __restrict__ out, int n) {
  int i = (blockIdx.x * blockDim.x + threadIdx.x) * 4;
  if (i < n) {
    float4 v = *(const float4*)(in + i);
    u16x4 o = { f2bf(v.x), f2bf(v.y), f2bf(v.z), f2bf(v.w) };
    *(u16x4*)(out + i) = o;
  }
}

// ---------------- transpose + cast: in K x N fp32 -> out N x K bf16 ----------------
__global__ void transpose_cast(const float* __restrict__ in, u16* __restrict__ out, int K, int N) {
  __shared__ float tile[32][33];
  int n0 = blockIdx.x * 32, k0 = blockIdx.y * 32;
  int tx = threadIdx.x, ty = threadIdx.y;
  for (int i = ty; i < 32; i += 8)
    tile[i][tx] = in[(size_t)(k0 + i) * N + n0 + tx];
  __syncthreads();
  for (int i = ty; i < 32; i += 8)
    out[(size_t)(n0 + i) * K + k0 + tx] = f2bf(tile[tx][i]);
}

// ---------------- bf16 transpose for V: qkv v-part (t,d) -> Vt (d,t) per kv head ----------------
__global__ void vtrans(const u16* __restrict__ qkv, u16* __restrict__ Vt) {
  __shared__ u16 tile[32][33];
  int kv = blockIdx.z;
  int t0 = blockIdx.x * 32, d0 = blockIdx.y * 32;
  int tx = threadIdx.x, ty = threadIdx.y;
  for (int i = ty; i < 32; i += 8)
    tile[i][tx] = qkv[(size_t)(t0 + i) * QKVD + VOFF + kv * HD + d0 + tx];
  __syncthreads();
  for (int i = ty; i < 32; i += 8)
    Vt[(size_t)(kv * HD + d0 + i) * T_SEQ + t0 + tx] = tile[tx][i];
}

// ---------------- NeoX RoPE in place on q,k parts of qkv (bf16) ----------------
__global__ void rope_kernel(u16* __restrict__ qkv, const int* __restrict__ positions) {
  int t = blockIdx.x;
  int h = blockIdx.y * 4 + (threadIdx.x >> 6);
  int i = threadIdx.x & 63;
  float pos = (float)positions[t];
  // inv_freq = 10000^(-i/64) = exp2(-i * log2(10000)/64)
  float freq = exp2f(-(float)i * (13.287712379549449f / 64.0f));
  float ang = pos * freq;
  float s, c;
  sincosf(ang, &s, &c);
  size_t off;
  if (h < NH) off = (size_t)t * QKVD + h * HD;
  else        off = (size_t)t * QKVD + KOFF + (h - NH) * HD;
  float x1 = bf2f(qkv[off + i]);
  float x2 = bf2f(qkv[off + 64 + i]);
  qkv[off + i]      = f2bf(x1 * c - x2 * s);
  qkv[off + 64 + i] = f2bf(x2 * c + x1 * s);
}

// ---------------- GEMM: A (MxK bf16 row-major) * B^T (NxK bf16 row-major) -> C (MxN) ----------------
template <bool BF16OUT>
__global__ __launch_bounds__(256) void gemm_bt(const u16* __restrict__ A, const u16* __restrict__ B,
                                               void* __restrict__ Cv, int M, int N, int K) {
  __shared__ __align__(16) u16 As[128 * 32];
  __shared__ __align__(16) u16 Bs[128 * 32];
  const int tid = threadIdx.x;
  const int w = tid >> 6, l = tid & 63;
  const int wr = w >> 1, wc = w & 1;
  const int lr = l & 15, lg = l >> 4;
  const int m0 = blockIdx.y * 128, n0 = blockIdx.x * 128;

  f32x4 acc[4][4] = {};

  const int r0 = w * 16 + (l >> 2);
  const int c0 = (l & 3) * 8;
  const u16* pA0 = A + (size_t)(m0 + r0) * K + c0;
  const u16* pA1 = A + (size_t)(m0 + 64 + r0) * K + c0;
  const u16* pB0 = B + (size_t)(n0 + r0) * K + c0;
  const u16* pB1 = B + (size_t)(n0 + 64 + r0) * K + c0;
  u16* dA0 = As + (w * 64) * 8;
  u16* dA1 = As + (256 + w * 64) * 8;
  u16* dB0 = Bs + (w * 64) * 8;
  u16* dB1 = Bs + (256 + w * 64) * 8;

  for (int k0 = 0; k0 < K; k0 += 32) {
    gl_lds16(pA0 + k0, dA0);
    gl_lds16(pA1 + k0, dA1);
    gl_lds16(pB0 + k0, dB0);
    gl_lds16(pB1 + k0, dB1);
    __syncthreads();
    s16x8 af[4], bfr[4];
#pragma unroll
    for (int i = 0; i < 4; i++) {
      af[i]  = *(const s16x8*)(As + (wr * 64 + i * 16 + lr) * 32 + lg * 8);
      bfr[i] = *(const s16x8*)(Bs + (wc * 64 + i * 16 + lr) * 32 + lg * 8);
    }
#pragma unroll
    for (int i = 0; i < 4; i++)
#pragma unroll
      for (int j = 0; j < 4; j++)
        acc[i][j] = __builtin_amdgcn_mfma_f32_16x16x32_bf16(af[i], bfr[j], acc[i][j], 0, 0, 0);
    __syncthreads();
  }
#pragma unroll
  for (int i = 0; i < 4; i++)
#pragma unroll
    for (int j = 0; j < 4; j++)
#pragma unroll
      for (int r = 0; r < 4; r++) {
        int row = m0 + wr * 64 + i * 16 + lg * 4 + r;
        int col = n0 + wc * 64 + j * 16 + lr;
        float v = acc[i][j][r];
        if (BF16OUT) ((u16*)Cv)[(size_t)row * N + col] = f2bf(v);
        else         ((float*)Cv)[(size_t)row * N + col] = v;
      }
}

// ---------------- flash attention: causal GQA, 16 q-rows per wave, KV tile = 64 ----------------
__global__ __launch_bounds__(256) void attn_fwd(const u16* __restrict__ qkv, const u16* __restrict__ Vt,
                                                u16* __restrict__ attnout) {
  __shared__ __align__(16) u16 plds[4][16 * 80];  // per-wave P tile, row stride 80 (160B, 16B-aligned)
  const int tid = threadIdx.x;
  const int w = tid >> 6, l = tid & 63;
  const int lr = l & 15, g = l >> 4;
  const int h = blockIdx.y;
  const int hkv = h >> 2;
  const int q0 = blockIdx.x * 64 + w * 16;
  const int q_abs = q0 + lr;
  const float scale = 0.08838834764831845f;

  // Q fragments: lane holds Q[q0+lr][kk*32 + g*8 .. +8]
  s16x8 qf[4];
  const u16* qbase = qkv + (size_t)(q0 + lr) * QKVD + h * HD + g * 8;
#pragma unroll
  for (int kk = 0; kk < 4; kk++)
    qf[kk] = *(const s16x8*)(qbase + kk * 32);

  f32x4 acc_o[8] = {};
  float m_run = -__builtin_inff();
  float l_run = 0.0f;

  u16* pw = &plds[w][0];
  const int ntiles = (q0 + 79) >> 6;
  for (int kt = 0; kt < ntiles; kt++) {
    const int kv0 = kt * 64;
    // S^T = K_tile * Q^T : lane holds S[q=q0+lr][kv = kv0 + ct*16 + g*4 + r]
    f32x4 sa[4];
#pragma unroll
    for (int ct = 0; ct < 4; ct++) {
      const u16* kbase = qkv + (size_t)(kv0 + ct * 16 + lr) * QKVD + KOFF + hkv * HD + g * 8;
      f32x4 a = {0.f, 0.f, 0.f, 0.f};
#pragma unroll
      for (int kk = 0; kk < 4; kk++) {
        s16x8 kf = *(const s16x8*)(kbase + kk * 32);
        a = __builtin_amdgcn_mfma_f32_16x16x32_bf16(kf, qf[kk], a, 0, 0, 0);
      }
      sa[ct] = a;
    }
    // scale + causal mask + online softmax
    float p[16];
    float pmax = -__builtin_inff();
#pragma unroll
    for (int ct = 0; ct < 4; ct++)
#pragma unroll
      for (int r = 0; r < 4; r++) {
        float s = sa[ct][r] * scale;
        int kv_abs = kv0 + ct * 16 + g * 4 + r;
        if (kv_abs > q_abs) s = -__builtin_inff();
        p[ct * 4 + r] = s;
        pmax = fmaxf(pmax, s);
      }
    pmax = fmaxf(pmax, __shfl_xor(pmax, 16, 64));
    pmax = fmaxf(pmax, __shfl_xor(pmax, 32, 64));
    float m_new = fmaxf(m_run, pmax);
    float fac = __expf(m_run - m_new);
    float psum = 0.f;
#pragma unroll
    for (int x = 0; x < 16; x++) {
      float e = __expf(p[x] - m_new);
      p[x] = e;
      psum += e;
    }
    psum += __shfl_xor(psum, 16, 64);
    psum += __shfl_xor(psum, 32, 64);
    l_run = l_run * fac + psum;
    m_run = m_new;
    // rescale accumulator (acc_o rows are q = g*4 + r; fac lives at lane (g*4+r))
    float fr[4];
#pragma unroll
    for (int r = 0; r < 4; r++) fr[r] = __shfl(fac, g * 4 + r, 64);
#pragma unroll
    for (int dt = 0; dt < 8; dt++)
#pragma unroll
      for (int r = 0; r < 4; r++) acc_o[dt][r] *= fr[r];
    // P -> bf16 -> per-wave LDS (row q=lr, col kv_rel)
#pragma unroll
    for (int ct = 0; ct < 4; ct++) {
      u16x4 pk = { f2bf(p[ct * 4 + 0]), f2bf(p[ct * 4 + 1]), f2bf(p[ct * 4 + 2]), f2bf(p[ct * 4 + 3]) };
      *(u16x4*)(pw + lr * 80 + ct * 16 + g * 4) = pk;
    }
    asm volatile("s_waitcnt lgkmcnt(0)" ::: "memory");
    s16x8 pa0 = *(const s16x8*)(pw + lr * 80 + g * 8);
    s16x8 pa1 = *(const s16x8*)(pw + lr * 80 + 32 + g * 8);
    // PV: O += P * V  (V read kv-contiguous from Vt)
#pragma unroll
    for (int dt = 0; dt < 8; dt++) {
      const u16* vb = Vt + (size_t)(hkv * HD + dt * 16 + lr) * T_SEQ + kv0 + g * 8;
      s16x8 v0 = *(const s16x8*)(vb);
      s16x8 v1 = *(const s16x8*)(vb + 32);
      acc_o[dt] = __builtin_amdgcn_mfma_f32_16x16x32_bf16(pa0, v0, acc_o[dt], 0, 0, 0);
      acc_o[dt] = __builtin_amdgcn_mfma_f32_16x16x32_bf16(pa1, v1, acc_o[dt], 0, 0, 0);
    }
  }
  // normalize + write out (attn layout: [t][h*128+d])
  float ln[4];
#pragma unroll
  for (int r = 0; r < 4; r++) ln[r] = __shfl(l_run, g * 4 + r, 64);
#pragma unroll
  for (int dt = 0; dt < 8; dt++)
#pragma unroll
    for (int r = 0; r < 4; r++) {
      int row = q0 + g * 4 + r;
      int col = h * HD + dt * 16 + lr;
      attnout[(size_t)row * HID + col] = f2bf(acc_o[dt][r] / ln[r]);
    }
}

extern "C" void kernel_launch(void* const* d_in, const int* in_sizes, int n_in,
                              void* d_out, int out_size, void* d_ws, size_t ws_size,
                              hipStream_t stream) {
  const int*   positions = (const int*)d_in[0];
  const float* X         = (const float*)d_in[1];
  const float* Wqkv      = (const float*)d_in[2];
  const float* Wo        = (const float*)d_in[3];
  float* out = (float*)d_out;

  char* ws = (char*)d_ws;
  size_t off = 0;
  u16* Xbf    = (u16*)(ws + off); off += (size_t)T_SEQ * HID * 2;      // 16 MB
  u16* Wqkvt  = (u16*)(ws + off); off += (size_t)QKVD * HID * 2;       // 48 MB
  u16* Wot    = (u16*)(ws + off); off += (size_t)HID * HID * 2;        // 32 MB
  u16* qkv    = (u16*)(ws + off); off += (size_t)T_SEQ * QKVD * 2;     // 24 MB
  u16* Vt     = (u16*)(ws + off); off += (size_t)NKV * HD * T_SEQ * 2; // 4 MB
  u16* attnb  = (u16*)(ws + off); off += (size_t)T_SEQ * HID * 2;      // 16 MB

  cast_f32_bf16<<<dim3((T_SEQ * HID) / (256 * 4)), dim3(256), 0, stream>>>(X, Xbf, T_SEQ * HID);
  transpose_cast<<<dim3(QKVD / 32, HID / 32), dim3(32, 8), 0, stream>>>(Wqkv, Wqkvt, HID, QKVD);
  transpose_cast<<<dim3(HID / 32, HID / 32), dim3(32, 8), 0, stream>>>(Wo, Wot, HID, HID);
  gemm_bt<true><<<dim3(QKVD / 128, T_SEQ / 128), dim3(256), 0, stream>>>(Xbf, Wqkvt, qkv, T_SEQ, QKVD, HID);
  rope_kernel<<<dim3(T_SEQ, 10), dim3(256), 0, stream>>>(qkv, positions);
  vtrans<<<dim3(T_SEQ / 32, HD / 32, NKV), dim3(32, 8), 0, stream>>>(qkv, Vt);
  attn_fwd<<<dim3(T_SEQ / 64, NH), dim3(256), 0, stream>>>(qkv, Vt, attnb);
  gemm_bt<false><<<dim3(HID / 128, T_SEQ / 128), dim3(256), 0, stream>>>(attnb, Wot, out, T_SEQ, HID, HID);
}

// Round 2
// 580.543 us; speedup vs baseline: 1.7112x; 1.7112x over previous
//
#include <hip/hip_runtime.h>
#include <hip/hip_bf16.h>
#include <math.h>

#define T_SEQ 2048
#define HID   4096
#define NH    32
#define NKV   8
#define HD    128
#define QKVD  6144
#define KOFF  4096
#define VOFF  5120

typedef unsigned short u16;
typedef unsigned int   u32;
typedef __attribute__((ext_vector_type(4))) float f32x4;
typedef __attribute__((ext_vector_type(8))) short s16x8;
typedef __attribute__((ext_vector_type(4))) unsigned short u16x4;

__device__ inline u16 f2bf(float f) {
  u32 u = __float_as_uint(f);
  u32 r = u + 0x7FFFu + ((u >> 16) & 1u);
  return (u16)(r >> 16);
}
__device__ inline float bf2f(u16 h) { return __uint_as_float(((u32)h) << 16); }

__device__ inline void gl_lds16(const void* g, void* l) {
  __builtin_amdgcn_global_load_lds((const __attribute__((address_space(1))) void*)g,
                                   (__attribute__((address_space(3))) void*)l, 16, 0, 0);
}

// ---------------- cast fp32 -> bf16 (vectorized) ----------------
__global__ void cast_f32_bf16(const float* __restrict__ in, u16* __restrict__ out, int n) {
  int i = (blockIdx.x * blockDim.x + threadIdx.x) * 4;
  if (i < n) {
    float4 v = *(const float4*)(in + i);
    u16x4 o = { f2bf(v.x), f2bf(v.y), f2bf(v.z), f2bf(v.w) };
    *(u16x4*)(out + i) = o;
  }
}

// ---------------- transpose + cast: in K x N fp32 -> out N x K bf16 ----------------
__global__ void transpose_cast(const float* __restrict__ in, u16* __restrict__ out, int K, int N) {
  __shared__ float tile[32][33];
  int n0 = blockIdx.x * 32, k0 = blockIdx.y * 32;
  int tx = threadIdx.x, ty = threadIdx.y;
  for (int i = ty; i < 32; i += 8)
    tile[i][tx] = in[(size_t)(k0 + i) * N + n0 + tx];
  __syncthreads();
  for (int i = ty; i < 32; i += 8)
    out[(size_t)(n0 + i) * K + k0 + tx] = f2bf(tile[tx][i]);
}

// ---------------- bf16 transpose for V: qkv v-part (t,d) -> Vt (d,t) per kv head ----------------
__global__ void vtrans(const u16* __restrict__ qkv, u16* __restrict__ Vt) {
  __shared__ u16 tile[32][33];
  int kv = blockIdx.z;
  int t0 = blockIdx.x * 32, d0 = blockIdx.y * 32;
  int tx = threadIdx.x, ty = threadIdx.y;
  for (int i = ty; i < 32; i += 8)
    tile[i][tx] = qkv[(size_t)(t0 + i) * QKVD + VOFF + kv * HD + d0 + tx];
  __syncthreads();
  for (int i = ty; i < 32; i += 8)
    Vt[(size_t)(kv * HD + d0 + i) * T_SEQ + t0 + tx] = tile[tx][i];
}

// ---------------- NeoX RoPE in place on q,k parts of qkv (bf16) ----------------
__global__ void rope_kernel(u16* __restrict__ qkv, const int* __restrict__ positions) {
  int t = blockIdx.x;
  int h = blockIdx.y * 4 + (threadIdx.x >> 6);
  int i = threadIdx.x & 63;
  float pos = (float)positions[t];
  float freq = exp2f(-(float)i * (13.287712379549449f / 64.0f));
  float ang = pos * freq;
  float s, c;
  sincosf(ang, &s, &c);
  size_t off;
  if (h < NH) off = (size_t)t * QKVD + h * HD;
  else        off = (size_t)t * QKVD + KOFF + (h - NH) * HD;
  float x1 = bf2f(qkv[off + i]);
  float x2 = bf2f(qkv[off + 64 + i]);
  qkv[off + i]      = f2bf(x1 * c - x2 * s);
  qkv[off + 64 + i] = f2bf(x2 * c + x1 * s);
}

// ---------------- GEMM: A (MxK bf16 row-major) * B^T (NxK bf16 row-major) -> C (MxN) ----------------
template <bool BF16OUT>
__global__ __launch_bounds__(256) void gemm_bt(const u16* __restrict__ A, const u16* __restrict__ B,
                                               void* __restrict__ Cv, int M, int N, int K) {
  __shared__ __align__(16) u16 As[128 * 32];
  __shared__ __align__(16) u16 Bs[128 * 32];
  const int tid = threadIdx.x;
  const int w = tid >> 6, l = tid & 63;
  const int wr = w >> 1, wc = w & 1;
  const int lr = l & 15, lg = l >> 4;
  const int m0 = blockIdx.y * 128, n0 = blockIdx.x * 128;

  f32x4 acc[4][4] = {};

  const int r0 = w * 16 + (l >> 2);
  const int c0 = (l & 3) * 8;
  const u16* pA0 = A + (size_t)(m0 + r0) * K + c0;
  const u16* pA1 = A + (size_t)(m0 + 64 + r0) * K + c0;
  const u16* pB0 = B + (size_t)(n0 + r0) * K + c0;
  const u16* pB1 = B + (size_t)(n0 + 64 + r0) * K + c0;
  u16* dA0 = As + (w * 64) * 8;
  u16* dA1 = As + (256 + w * 64) * 8;
  u16* dB0 = Bs + (w * 64) * 8;
  u16* dB1 = Bs + (256 + w * 64) * 8;

  for (int k0 = 0; k0 < K; k0 += 32) {
    gl_lds16(pA0 + k0, dA0);
    gl_lds16(pA1 + k0, dA1);
    gl_lds16(pB0 + k0, dB0);
    gl_lds16(pB1 + k0, dB1);
    __syncthreads();
    s16x8 af[4], bfr[4];
#pragma unroll
    for (int i = 0; i < 4; i++) {
      af[i]  = *(const s16x8*)(As + (wr * 64 + i * 16 + lr) * 32 + lg * 8);
      bfr[i] = *(const s16x8*)(Bs + (wc * 64 + i * 16 + lr) * 32 + lg * 8);
    }
#pragma unroll
    for (int i = 0; i < 4; i++)
#pragma unroll
      for (int j = 0; j < 4; j++)
        acc[i][j] = __builtin_amdgcn_mfma_f32_16x16x32_bf16(af[i], bfr[j], acc[i][j], 0, 0, 0);
    __syncthreads();
  }
#pragma unroll
  for (int i = 0; i < 4; i++)
#pragma unroll
    for (int j = 0; j < 4; j++)
#pragma unroll
      for (int r = 0; r < 4; r++) {
        int row = m0 + wr * 64 + i * 16 + lg * 4 + r;
        int col = n0 + wc * 64 + j * 16 + lr;
        float v = acc[i][j][r];
        if (BF16OUT) ((u16*)Cv)[(size_t)row * N + col] = f2bf(v);
        else         ((float*)Cv)[(size_t)row * N + col] = v;
      }
}

// ---------------- flash attention, LDS-staged + double-buffered + swizzled ----------------
// Block: 4 waves x 16 q rows = 64 q rows per q-tile; each block processes q-tile pair
// (qt, 31-qt) sequentially -> uniformly 33 kv-tiles per block. KV tile = 64.
__device__ inline void stage_tiles(const u16* __restrict__ qkv, const u16* __restrict__ Vt,
                                   u16* Kb, u16* Vb, int kv0, int hkv, int w, int l) {
  const int krow_l = l >> 4;
  const int kcb = (l & 15) << 4;
  const int vrow_l = l >> 3;
  const int vcb = (l & 7) << 4;
#pragma unroll
  for (int c = 0; c < 4; c++) {
    int row = c * 16 + w * 4 + krow_l;
    const char* src = (const char*)(qkv + (size_t)(kv0 + row) * QKVD + KOFF + hkv * HD) +
                      (kcb ^ ((row & 7) << 4));
    gl_lds16(src, (char*)Kb + (c * 16 + w * 4) * 256);
  }
#pragma unroll
  for (int c = 0; c < 4; c++) {
    int row = c * 32 + w * 8 + vrow_l;
    const char* src = (const char*)(Vt + (size_t)(hkv * HD + row) * T_SEQ + kv0) +
                      (vcb ^ ((row & 7) << 4));
    gl_lds16(src, (char*)Vb + (c * 32 + w * 8) * 128);
  }
}

__global__ __launch_bounds__(256) void attn_fwd(const u16* __restrict__ qkv, const u16* __restrict__ Vt,
                                                u16* __restrict__ attnout) {
  __shared__ __align__(16) u16 Ks[2][64 * 128];
  __shared__ __align__(16) u16 Vs[2][128 * 64];
  __shared__ __align__(16) u16 plds[4][16 * 72];
  const int tid = threadIdx.x;
  const int w = tid >> 6, l = tid & 63;
  const int lr = l & 15, g = l >> 4;
  const int h = blockIdx.y;
  const int hkv = h >> 2;
  const int swzl = (lr & 7) << 4;
  const float scale = 0.08838834764831845f;
  u16* pw = &plds[w][0];

  for (int seg = 0; seg < 2; seg++) {
    const int qt = (seg == 0) ? blockIdx.x : (31 - blockIdx.x);
    const int q0 = qt * 64 + w * 16;
    const int q_abs = q0 + lr;

    s16x8 qf[4];
    const u16* qbase = qkv + (size_t)(q0 + lr) * QKVD + h * HD + g * 8;
#pragma unroll
    for (int kk = 0; kk < 4; kk++) qf[kk] = *(const s16x8*)(qbase + kk * 32);

    f32x4 acc_o[8] = {};
    float m_run = -__builtin_inff();
    float l_run = 0.0f;
    const int nt = qt + 1;

    stage_tiles(qkv, Vt, Ks[0], Vs[0], 0, hkv, w, l);
    asm volatile("s_waitcnt vmcnt(0)" ::: "memory");
    __syncthreads();
    int cur = 0;
    for (int kt = 0; kt < nt; kt++) {
      const int kv0 = kt * 64;
      if (kt + 1 < nt)
        stage_tiles(qkv, Vt, Ks[cur ^ 1], Vs[cur ^ 1], kv0 + 64, hkv, w, l);
      const bool masked = (kt == qt);

      // QK^T (swapped: mfma(K,Q) -> lane owns q=q0+lr row, 16 kv values)
      f32x4 sa[4];
      const char* kb = (const char*)Ks[cur];
#pragma unroll
      for (int ct = 0; ct < 4; ct++) {
        f32x4 a = {0.f, 0.f, 0.f, 0.f};
#pragma unroll
        for (int kk = 0; kk < 4; kk++) {
          s16x8 kf = *(const s16x8*)(kb + (ct * 16 + lr) * 256 + (((kk << 6) + (g << 4)) ^ swzl));
          a = __builtin_amdgcn_mfma_f32_16x16x32_bf16(kf, qf[kk], a, 0, 0, 0);
        }
        sa[ct] = a;
      }

      // online softmax
      float p[16];
      float pmax = -__builtin_inff();
#pragma unroll
      for (int ct = 0; ct < 4; ct++)
#pragma unroll
        for (int r = 0; r < 4; r++) {
          float s = sa[ct][r] * scale;
          if (masked) {
            int kv_abs = kv0 + ct * 16 + g * 4 + r;
            if (kv_abs > q_abs) s = -__builtin_inff();
          }
          p[ct * 4 + r] = s;
          pmax = fmaxf(pmax, s);
        }
      pmax = fmaxf(pmax, __shfl_xor(pmax, 16, 64));
      pmax = fmaxf(pmax, __shfl_xor(pmax, 32, 64));
      float m_new = fmaxf(m_run, pmax);
      float fac = __expf(m_run - m_new);
      float psum = 0.f;
#pragma unroll
      for (int x = 0; x < 16; x++) {
        float e = __expf(p[x] - m_new);
        p[x] = e;
        psum += e;
      }
      psum += __shfl_xor(psum, 16, 64);
      psum += __shfl_xor(psum, 32, 64);
      l_run = l_run * fac + psum;
      m_run = m_new;
      float fr[4];
#pragma unroll
      for (int r = 0; r < 4; r++) fr[r] = __shfl(fac, g * 4 + r, 64);
#pragma unroll
      for (int dt = 0; dt < 8; dt++)
#pragma unroll
        for (int r = 0; r < 4; r++) acc_o[dt][r] *= fr[r];

      // P -> bf16 -> per-wave LDS (stride 72 u16: conflict-free), repack to A-fragments
#pragma unroll
      for (int ct = 0; ct < 4; ct++) {
        u16x4 pk = { f2bf(p[ct * 4 + 0]), f2bf(p[ct * 4 + 1]), f2bf(p[ct * 4 + 2]), f2bf(p[ct * 4 + 3]) };
        *(u16x4*)(pw + lr * 72 + ct * 16 + g * 4) = pk;
      }
      asm volatile("s_waitcnt lgkmcnt(0)" ::: "memory");
      __builtin_amdgcn_sched_barrier(0);
      s16x8 pa0 = *(const s16x8*)(pw + lr * 72 + g * 8);
      s16x8 pa1 = *(const s16x8*)(pw + lr * 72 + 32 + g * 8);

      // PV from swizzled Vs
      const char* vbb = (const char*)Vs[cur];
#pragma unroll
      for (int dt = 0; dt < 8; dt++) {
        s16x8 v0 = *(const s16x8*)(vbb + (dt * 16 + lr) * 128 + ((g << 4) ^ swzl));
        s16x8 v1 = *(const s16x8*)(vbb + (dt * 16 + lr) * 128 + ((64 + (g << 4)) ^ swzl));
        acc_o[dt] = __builtin_amdgcn_mfma_f32_16x16x32_bf16(pa0, v0, acc_o[dt], 0, 0, 0);
        acc_o[dt] = __builtin_amdgcn_mfma_f32_16x16x32_bf16(pa1, v1, acc_o[dt], 0, 0, 0);
      }
      asm volatile("s_waitcnt vmcnt(0)" ::: "memory");
      __syncthreads();
      cur ^= 1;
    }

    // normalize + write out
    float ln[4];
#pragma unroll
    for (int r = 0; r < 4; r++) ln[r] = __shfl(l_run, g * 4 + r, 64);
#pragma unroll
    for (int dt = 0; dt < 8; dt++)
#pragma unroll
      for (int r = 0; r < 4; r++) {
        int row = q0 + g * 4 + r;
        int col = h * HD + dt * 16 + lr;
        attnout[(size_t)row * HID + col] = f2bf(acc_o[dt][r] / ln[r]);
      }
  }
}

extern "C" void kernel_launch(void* const* d_in, const int* in_sizes, int n_in,
                              void* d_out, int out_size, void* d_ws, size_t ws_size,
                              hipStream_t stream) {
  const int*   positions = (const int*)d_in[0];
  const float* X         = (const float*)d_in[1];
  const float* Wqkv      = (const float*)d_in[2];
  const float* Wo        = (const float*)d_in[3];
  float* out = (float*)d_out;

  char* ws = (char*)d_ws;
  size_t off = 0;
  u16* Xbf    = (u16*)(ws + off); off += (size_t)T_SEQ * HID * 2;
  u16* Wqkvt  = (u16*)(ws + off); off += (size_t)QKVD * HID * 2;
  u16* Wot    = (u16*)(ws + off); off += (size_t)HID * HID * 2;
  u16* qkv    = (u16*)(ws + off); off += (size_t)T_SEQ * QKVD * 2;
  u16* Vt     = (u16*)(ws + off); off += (size_t)NKV * HD * T_SEQ * 2;
  u16* attnb  = (u16*)(ws + off); off += (size_t)T_SEQ * HID * 2;

  cast_f32_bf16<<<dim3((T_SEQ * HID) / (256 * 4)), dim3(256), 0, stream>>>(X, Xbf, T_SEQ * HID);
  transpose_cast<<<dim3(QKVD / 32, HID / 32), dim3(32, 8), 0, stream>>>(Wqkv, Wqkvt, HID, QKVD);
  transpose_cast<<<dim3(HID / 32, HID / 32), dim3(32, 8), 0, stream>>>(Wo, Wot, HID, HID);
  gemm_bt<true><<<dim3(QKVD / 128, T_SEQ / 128), dim3(256), 0, stream>>>(Xbf, Wqkvt, qkv, T_SEQ, QKVD, HID);
  rope_kernel<<<dim3(T_SEQ, 10), dim3(256), 0, stream>>>(qkv, positions);
  vtrans<<<dim3(T_SEQ / 32, HD / 32, NKV), dim3(32, 8), 0, stream>>>(qkv, Vt);
  attn_fwd<<<dim3(16, 32), dim3(256), 0, stream>>>(qkv, Vt, attnb);
  gemm_bt<false><<<dim3(HID / 128, T_SEQ / 128), dim3(256), 0, stream>>>(attnb, Wot, out, T_SEQ, HID, HID);
}